// Round 10
// baseline (649.052 us; speedup 1.0000x reference)
//
#include <hip/hip_runtime.h>
#include <hip/hip_bf16.h>
#include <stdint.h>

// ---------------- problem constants ----------------
constexpr int NN = 100000;     // nodes
constexpr int NE = 1600000;    // edges
constexpr int NG = 64;         // graphs
constexpr int S  = 192;        // row stride (elements) for node-feature buffers
constexpr int NB_SCAN = 98;    // ceil(100000/1024)
constexpr int NN8 = 100352;    // per-copy stride for replicated counters
constexpr unsigned int ZOFF = (unsigned int)NN * 384u;   // byte offset of the zero row

// prep kernel grid sections (indeg+slot FIRST | convx | convw(W0..W2) | nstart)
constexpr int PREP_INDEG_BLK = 1563;    // ceil(NE/4/256), 4 edges/thread
constexpr int PREP_CONVX_BLK = 12500;   // NN*32/256
constexpr int PREP_CONVW_BLK = 384;     // (24576+36864+36864)/256
constexpr int PREP_GB_BLK    = 391;     // ceil(NN/256)
constexpr int PREP_GRID = PREP_INDEG_BLK + PREP_CONVX_BLK + PREP_CONVW_BLK + PREP_GB_BLK;

// E-GEMM geometry
constexpr int EG_BLOCKS = 391;            // ceil(NN/256), 256 src rows per block
constexpr int HROW = 50048;               // hist row length in u32 (EG_BLOCKS*256/2)
constexpr int QROW = HROW / 4;            // 12512

typedef __bf16 bf16x8 __attribute__((ext_vector_type(8)));
typedef float  f32x16 __attribute__((ext_vector_type(16)));
typedef float  f32x2  __attribute__((ext_vector_type(2)));

union U16x4 { uint4 u; bf16x8 b; };

// bf16(packed in uint halves) <-> f32 helpers
__device__ __forceinline__ float bl(unsigned int u) { return __uint_as_float(u << 16); }
__device__ __forceinline__ float bh(unsigned int u) { return __uint_as_float(u & 0xffff0000u); }
__device__ __forceinline__ float b16f(unsigned short u) { return __uint_as_float(((unsigned int)u) << 16); }
__device__ __forceinline__ unsigned int fb(float f) {  // f32 -> bf16 bits, RTNE
    unsigned int u = __float_as_uint(f);
    return (u + 0x7fffu + ((u >> 16) & 1u)) >> 16;
}
// packed bf16 relu: v_pk_max_f16 on raw bits decides on sign/zero only — exact for bf16.
__device__ __forceinline__ unsigned int prelu(unsigned int u) {
    unsigned int r;
    asm("v_pk_max_f16 %0, %1, %2" : "=v"(r) : "v"(u), "v"(0u));
    return r;
}
// two u16 counts -> packed bf16 pair (exact for counts <= 256)
__device__ __forceinline__ unsigned int cnt2bf(unsigned int h) {
    float f0 = (float)(h & 0xffffu);
    float f1 = (float)(h >> 16);
    return (__float_as_uint(f0) >> 16) | (__float_as_uint(f1) & 0xffff0000u);
}

// ---------------- fused preprocessing: indeg8+slot | convx | convw | nstart ----------------
// indeg counters replicated 8x, copy chosen by blockIdx&7 (presumed XCD): each copy's
// cache lines stay in one XCD's L2 -> no cross-XCD ping-pong on the atomic RMWs.
// Copy selector is a deterministic function of blockIdx, recomputed by k_fill, so
// correctness does NOT depend on the actual XCD mapping.
__global__ __launch_bounds__(256) void k_prep(const float* __restrict__ x,
                                              const int* __restrict__ ei,
                                              const int* __restrict__ bat,
                                              const float* __restrict__ W0, const float* __restrict__ W1,
                                              const float* __restrict__ W2,
                                              unsigned short* __restrict__ A_,
                                              int* __restrict__ indeg8, int* __restrict__ slot,
                                              unsigned short* __restrict__ T0, unsigned short* __restrict__ T1,
                                              unsigned short* __restrict__ T2,
                                              int* __restrict__ nstart) {
    const int b = blockIdx.x;
    if (b < PREP_INDEG_BLK) {
        int e4 = (b * 256 + threadIdx.x) * 4;
        if (e4 < NE) {
            int* cp = indeg8 + (b & 7) * NN8;
            int4 d = *(const int4*)(ei + NE + e4);
            int4 sl;
            sl.x = atomicAdd(&cp[d.x], 1);
            sl.y = atomicAdd(&cp[d.y], 1);
            sl.z = atomicAdd(&cp[d.z], 1);
            sl.w = atomicAdd(&cp[d.w], 1);
            *(int4*)(slot + e4) = sl;
        }
    } else if (b < PREP_INDEG_BLK + PREP_CONVX_BLK) {
        int id = (b - PREP_INDEG_BLK) * 256 + threadIdx.x;
        if (id < 96) ((unsigned int*)(A_ + (size_t)NN * S))[id] = 0u;   // zero sentinel row
        int row = id >> 5, c4 = id & 31;
        float4 v = ((const float4*)x)[id];
        uint2 a;
        a.x = fb(v.x) | (fb(v.y) << 16);
        a.y = fb(v.z) | (fb(v.w) << 16);
        *(uint2*)(A_ + row * S + c4 * 4) = a;
    } else if (b < PREP_INDEG_BLK + PREP_CONVX_BLK + PREP_CONVW_BLK) {
        int id = (b - PREP_INDEG_BLK - PREP_CONVX_BLK) * 256 + threadIdx.x;
        const float* W; unsigned short* T; int N, base;
        if      (id < 24576) { W = W0; T = T0; N = 192; base = 0;     }
        else if (id < 61440) { W = W1; T = T1; N = 192; base = 24576; }
        else                 { W = W2; T = T2; N = 192; base = 61440; }
        int lid = id - base;
        int ci = lid >> 3, j = lid & 7;
        int kc = ci / N, n = ci % N;
        T[lid] = (unsigned short)fb(W[(kc * 8 + j) * N + n]);
    } else {
        // nstart[g] = first node n with bat[n] >= g (batch sorted); empty graphs ok
        int n = (b - PREP_INDEG_BLK - PREP_CONVX_BLK - PREP_CONVW_BLK) * 256 + threadIdx.x;
        if (n < NN) {
            int b0 = bat[n];
            int bprev = (n == 0) ? -1 : bat[n - 1];
            for (int g = bprev + 1; g <= b0; g++) nstart[g] = n;
            if (n == NN - 1)
                for (int g = b0 + 1; g < NG; g++) nstart[g] = NN;
        }
    }
}

// ---------------- scan: merge 8 counter copies -> indeg, pxcd, offs; zero sums ----------------
__global__ __launch_bounds__(1024) void k_scan1(const int* __restrict__ indeg8,
                                                int* __restrict__ indeg,
                                                unsigned short* __restrict__ pxcd,
                                                int* __restrict__ offs,
                                                int* __restrict__ partials,
                                                float* __restrict__ zero_region) {
    __shared__ int s[1024];
    int t = threadIdx.x;
    int gid = blockIdx.x * 1024 + t;
    int v = 0;
    if (gid < NN) {
        int run = 0;
#pragma unroll
        for (int x = 0; x < 8; x++) {
            int c = indeg8[x * NN8 + gid];
            pxcd[x * NN8 + gid] = (unsigned short)run;   // exclusive prefix over copies
            run += c;
        }
        v = run;
        indeg[gid] = run;
    }
    if (blockIdx.x == 0) {   // fold: zero sums+cnt+degsum (12,416 floats, contiguous)
        for (int i = t; i < 12416; i += 1024) zero_region[i] = 0.f;
    }
    s[t] = v;
    __syncthreads();
    for (int d = 1; d < 1024; d <<= 1) {
        int tv = (t >= d) ? s[t - d] : 0;
        __syncthreads();
        s[t] += tv;
        __syncthreads();
    }
    if (gid < NN) offs[gid + 1] = s[t];
    if (t == 1023) partials[blockIdx.x] = s[1023];
}

// true exclusive offset of node j (offs holds block-local inclusive scans; part = exclusive
// prefix of block partials, published by k_fill block 0)
__device__ __forceinline__ int toff(const int* __restrict__ offs, const int* __restrict__ part, int j) {
    return j ? (offs[j] + part[(j - 1) >> 10]) : 0;
}

// ---------------- CSR fill (98-entry partial prefix recomputed in LDS) ----------------
__global__ __launch_bounds__(256) void k_fill(const int* __restrict__ ei, const int* __restrict__ offs,
                                              const int* __restrict__ praw,
                                              const int* __restrict__ slot,
                                              const unsigned short* __restrict__ pxcd,
                                              int* __restrict__ csr,
                                              int* __restrict__ part2) {
    __shared__ int s[128];
    __shared__ int spx[128];
    const int t = threadIdx.x;
    int v = 0;
    if (t < 128) {
        v = (t < NB_SCAN) ? praw[t] : 0;
        s[t] = v;
    }
    __syncthreads();
    for (int d = 1; d < 128; d <<= 1) {
        int tv = (t < 128 && t >= d) ? s[t - d] : 0;
        __syncthreads();
        if (t < 128) s[t] += tv;
        __syncthreads();
    }
    if (t < 128) spx[t] = s[t] - v;          // exclusive prefix of partials
    __syncthreads();
    if (blockIdx.x == 0 && t < NB_SCAN) part2[t] = spx[t];

    int e4 = (blockIdx.x * 256 + t) * 4;
    if (e4 >= NE) return;
    const unsigned short* px = pxcd + (size_t)((e4 >> 10) & 7) * NN8;   // prep copy of this edge block
    int4 sv = *(const int4*)(ei + e4);
    int4 dv = *(const int4*)(ei + NE + e4);
    int4 sl = *(const int4*)(slot + e4);
    csr[(dv.x ? offs[dv.x] + spx[(dv.x - 1) >> 10] : 0) + px[dv.x] + sl.x] = sv.x;
    csr[(dv.y ? offs[dv.y] + spx[(dv.y - 1) >> 10] : 0) + px[dv.y] + sl.y] = sv.y;
    csr[(dv.z ? offs[dv.z] + spx[(dv.z - 1) >> 10] : 0) + px[dv.z] + sl.z] = sv.z;
    csr[(dv.w ? offs[dv.w] + spx[(dv.w - 1) >> 10] : 0) + px[dv.w] + sl.w] = sv.w;
}

// ---------------- aggregation (layers 0..2) — round-7-proven structure ----------------
__global__ __launch_bounds__(256, 8) void k_agg192(const unsigned short* __restrict__ Ain,
                                                   unsigned short* __restrict__ Yout,
                                                   const int* __restrict__ offs,
                                                   const int* __restrict__ part,
                                                   const int* __restrict__ indeg,
                                                   const int* __restrict__ csr) {
    const int w = threadIdx.x >> 6, lane = threadIdx.x & 63;
    const int i = __builtin_amdgcn_readfirstlane(blockIdx.x * 4 + w);
    const bool act = lane < 48;
    const int deg   = __builtin_amdgcn_readfirstlane(indeg[i]);
    const int start = __builtin_amdgcn_readfirstlane(toff(offs, part, i));
    const int fo = (act ? lane : 47) * 8;
    const char* Ab = (const char*)Ain;

    f32x2 A01, A23;
    {
        uint2 p = *(const uint2*)(Ab + (size_t)i * 384 + fo);
        const float ed = 1e-7f * (float)deg;
        A01 = (f32x2){bl(p.x) + ed, bh(p.x) + ed};
        A23 = (f32x2){bl(p.y) + ed, bh(p.y) + ed};
    }

    const int* ecsr = csr + start;
    for (int e = 0; e < deg; e += 16) {
        unsigned int off[16];
#pragma unroll
        for (int k = 0; k < 16; k++) {
            int v = ecsr[e + k];
            off[k] = (e + k < deg) ? (unsigned int)v * 384u : ZOFF;
        }
        uint2 p[16];
#pragma unroll
        for (int k = 0; k < 16; k++)
            p[k] = *(const uint2*)(Ab + (size_t)off[k] + fo);
#pragma unroll
        for (int k = 0; k < 16; k++) {
            unsigned int rx = prelu(p[k].x), ry = prelu(p[k].y);
            A01 += (f32x2){bl(rx), bh(rx)};
            A23 += (f32x2){bl(ry), bh(ry)};
        }
    }
    if (act) {
        uint2 o;
        o.x = fb(A01.x) | (fb(A01.y) << 16);
        o.y = fb(A23.x) | (fb(A23.y) << 16);
        *(uint2*)(Yout + (size_t)i * S + lane * 4) = o;
    }
}

__global__ __launch_bounds__(256, 8) void k_agg128(const unsigned short* __restrict__ Ain,
                                                   unsigned short* __restrict__ Yout,
                                                   const int* __restrict__ offs,
                                                   const int* __restrict__ part,
                                                   const int* __restrict__ indeg,
                                                   const int* __restrict__ csr) {
    const int w = threadIdx.x >> 6, lane = threadIdx.x & 63;
    const int i = __builtin_amdgcn_readfirstlane(blockIdx.x * 4 + w);
    const int deg   = __builtin_amdgcn_readfirstlane(indeg[i]);
    const int start = __builtin_amdgcn_readfirstlane(toff(offs, part, i));
    const int fo = lane * 4;
    const char* Ab = (const char*)Ain;

    f32x2 A01;
    {
        unsigned int p = *(const unsigned int*)(Ab + (size_t)i * 384 + fo);
        const float ed = 1e-7f * (float)deg;
        A01 = (f32x2){bl(p) + ed, bh(p) + ed};
    }

    const int* ecsr = csr + start;
    for (int e = 0; e < deg; e += 16) {
        unsigned int off[16];
#pragma unroll
        for (int k = 0; k < 16; k++) {
            int v = ecsr[e + k];
            off[k] = (e + k < deg) ? (unsigned int)v * 384u : ZOFF;
        }
        unsigned int q[16];
#pragma unroll
        for (int k = 0; k < 16; k++)
            q[k] = *(const unsigned int*)(Ab + (size_t)off[k] + fo);
#pragma unroll
        for (int k = 0; k < 16; k++) {
            unsigned int r = prelu(q[k]);
            A01 += (f32x2){bl(r), bh(r)};
        }
    }
    *(unsigned int*)(Yout + (size_t)i * S + lane * 2) =
        fb(A01.x) | (fb(A01.y) << 16);
}

// ---------------- GEMM: h = y @ W + b (layers 0..2) ----------------
template <int K, int N>
__global__ __launch_bounds__(256) void k_gemm(const unsigned short* __restrict__ Yin,
                                              const unsigned short* __restrict__ WtC,
                                              const float* __restrict__ bias,
                                              unsigned short* __restrict__ Aout) {
    static_assert(K % 16 == 0 && N % 32 == 0, "");
    const int w = threadIdx.x >> 6, lane = threadIdx.x & 63;
    const int rt = blockIdx.x * 4 + w;
    if (rt >= (NN / 32)) return;
    const int hl = lane >> 5, lr = lane & 31;
    const int row0 = rt * 32;
    f32x16 acc[N / 32];
#pragma unroll
    for (int c = 0; c < N / 32; c++)
#pragma unroll
        for (int r = 0; r < 16; r++) acc[c][r] = 0.f;

    const unsigned short* ap = Yin + (row0 + lr) * S + hl * 8;
    const uint4* b4 = (const uint4*)WtC;
#pragma unroll
    for (int ks = 0; ks < K / 16; ks++) {
        U16x4 a;
        a.u = *(const uint4*)(ap + ks * 16);
#pragma unroll
        for (int c = 0; c < N / 32; c++) {
            U16x4 b;
            b.u = b4[(ks * 2 + hl) * N + c * 32 + lr];
            acc[c] = __builtin_amdgcn_mfma_f32_32x32x16_bf16(a.b, b.b, acc[c], 0, 0, 0);
        }
    }
#pragma unroll
    for (int c = 0; c < N / 32; c++) {
        const int col = c * 32 + lr;
        const float bc = bias[col];
#pragma unroll
        for (int r = 0; r < 16; r++) {
            const int row = row0 + (r & 3) + 8 * (r >> 2) + 4 * hl;
            Aout[row * S + col] = (unsigned short)fb(acc[c][r] + bc);
        }
    }
}

// ---------------- fused hist + pool (both depend only on layer-2 output) ----------------
__global__ __launch_bounds__(256) void k_histpool(const int* __restrict__ csr,
                                                  const int* __restrict__ offs,
                                                  const int* __restrict__ part,
                                                  const int* __restrict__ nstart,
                                                  unsigned int* __restrict__ hist,
                                                  const unsigned short* __restrict__ X3,
                                                  const int* __restrict__ bat,
                                                  const int* __restrict__ indeg,
                                                  float* __restrict__ sums, float* __restrict__ cnt,
                                                  float* __restrict__ degsum) {
    const int b = blockIdx.x;
    if (b < 256) {
        const int g = b >> 2, q = b & 3;
        unsigned int* hrow = hist + (size_t)g * HROW;
        const unsigned int q0 = q * QROW;
        for (int i = threadIdx.x; i < QROW; i += 256) hrow[q0 + i] = 0u;
        __syncthreads();
        const int s0 = toff(offs, part, nstart[g]);
        const int s1 = (g == NG - 1) ? NE : toff(offs, part, nstart[g + 1]);
        for (int p = s0 + threadIdx.x; p < s1; p += 256) {
            int src = csr[p];
            unsigned int h = (unsigned int)src >> 1;
            if (h - q0 < (unsigned int)QROW)
                atomicAdd(&hrow[h], 1u << (16 * (src & 1)));
        }
    } else {
        const int pb = b - 256;        // 2000 blocks x 50 nodes
        const int f = threadIdx.x;     // 192 features (64 lanes idle)
        if (f >= 192) return;
        int n0 = pb * 50;
        int n1 = min(n0 + 50, NN);
        int cur = bat[n0];
        float acc = 0.f;
        int run = 0, dacc = 0;
        for (int n = n0; n < n1; n++) {
            int g = bat[n];
            if (g != cur) {
                atomicAdd(&sums[cur * 192 + f], acc);
                if (f == 0) { atomicAdd(&cnt[cur], (float)run); atomicAdd(&degsum[cur], (float)dacc); }
                acc = 0.f; run = 0; dacc = 0; cur = g;
            }
            acc += b16f(X3[(size_t)n * S + f]);
            run++;
            if (f == 0) dacc += indeg[n];
        }
        atomicAdd(&sums[cur * 192 + f], acc);
        if (f == 0) { atomicAdd(&cnt[cur], (float)run); atomicAdd(&degsum[cur], (float)dacc); }
    }
}

// ---------------- layer-3 E-GEMM: P[g][f] += count(j->g) * relu(x3[j][f]) ----------------
__global__ __launch_bounds__(384) void k_egemm(const unsigned short* __restrict__ X3,
                                               const unsigned int* __restrict__ hist,
                                               float* __restrict__ partials) {
    const int wv = threadIdx.x >> 6, lane = threadIdx.x & 63;
    const int b = blockIdx.x;
    const int j0 = b * 256;
    const int hl = lane >> 5, lr = lane & 31;
    const int feat = wv * 32 + lr;
    f32x16 acc[2];
#pragma unroll
    for (int m = 0; m < 2; m++)
#pragma unroll
        for (int r = 0; r < 16; r++) acc[m][r] = 0.f;

    for (int kk = 0; kk < 16; kk++) {
        const int jh = (j0 >> 1) + kk * 8 + hl * 4;
        U16x4 af[2];
#pragma unroll
        for (int m = 0; m < 2; m++) {
            uint4 h = *(const uint4*)(hist + (size_t)(m * 32 + lr) * HROW + jh);
            af[m].u = (uint4){cnt2bf(h.x), cnt2bf(h.y), cnt2bf(h.z), cnt2bf(h.w)};
        }
        U16x4 bf;
#pragma unroll
        for (int tp = 0; tp < 4; tp++) {
            int je = j0 + kk * 16 + hl * 8 + tp * 2;
            int ja = min(je, NN), jb = min(je + 1, NN);   // sentinel zero row
            unsigned int u0 = X3[(size_t)ja * S + feat];
            unsigned int u1 = X3[(size_t)jb * S + feat];
            ((unsigned int*)&bf.u)[tp] = prelu(u0 | (u1 << 16));
        }
#pragma unroll
        for (int m = 0; m < 2; m++)
            acc[m] = __builtin_amdgcn_mfma_f32_32x32x16_bf16(af[m].b, bf.b, acc[m], 0, 0, 0);
    }
    float* pb = partials + (size_t)b * 12288;
#pragma unroll
    for (int m = 0; m < 2; m++)
#pragma unroll
        for (int r = 0; r < 16; r++) {
            const int g = m * 32 + (r & 3) + 8 * (r >> 2) + 4 * hl;
            pb[g * 192 + feat] = acc[m][r];
        }
}

// ---------------- head (fused partial-reduce + 2-layer MLP + log_softmax) ----------------
__global__ __launch_bounds__(192) void k_head(const float* __restrict__ sums,
                                              const float* __restrict__ partials,
                                              const float* __restrict__ cnt, const float* __restrict__ degsum,
                                              const float* __restrict__ W3, const float* __restrict__ b3,
                                              const float* __restrict__ Wfc, const float* __restrict__ bfc,
                                              float* __restrict__ out) {
    __shared__ float py[192];
    __shared__ float tl[128];
    __shared__ float lg[10];
    const int g = blockIdx.x, t = threadIdx.x;   // 192 threads = 192 feats
    const float inv = 1.f / fmaxf(cnt[g], 1.f);
    const float ed = 1e-7f * degsum[g];
    const float* pp = partials + g * 192 + t;
    float s0 = 0.f, s1 = 0.f, s2 = 0.f, s3 = 0.f;
    int p = 0;
    for (; p + 4 <= EG_BLOCKS; p += 4) {
        s0 += pp[(size_t)(p + 0) * 12288];
        s1 += pp[(size_t)(p + 1) * 12288];
        s2 += pp[(size_t)(p + 2) * 12288];
        s3 += pp[(size_t)(p + 3) * 12288];
    }
    for (; p < EG_BLOCKS; p++) s0 += pp[(size_t)p * 12288];
    py[t] = (sums[g * 192 + t] + ((s0 + s1) + (s2 + s3)) + ed) * inv;
    __syncthreads();
    if (t < 128) {
        float tf = b3[t];
        for (int k = 0; k < 192; k++) tf += py[k] * W3[k * 128 + t];
        tl[t] = tf;
    }
    __syncthreads();
    if (t < 10) {
        float sf = bfc[t];
        for (int f = 0; f < 128; f++) sf += tl[f] * Wfc[f * 10 + t];
        lg[t] = sf;
    }
    __syncthreads();
    if (t < 10) {
        float m = lg[0];
        for (int k = 1; k < 10; k++) m = fmaxf(m, lg[k]);
        float se = 0.f;
        for (int k = 0; k < 10; k++) se += expf(lg[k] - m);
        out[g * 10 + t] = lg[t] - m - logf(se);
    }
}

// ---------------- workspace layout (bytes) ----------------
// A1 region phases: [slot 6.4MB | indeg8 3.21MB | pxcd 1.6MB] (pre-CSR, all dead after
// k_fill) -> y buffer (agg/gemm) -> hist/partials (layer 3). A0 carries the zero row.
constexpr size_t A0_OFF      = 0;                   // 38,400,384 (incl zero row NN)
constexpr size_t A1_OFF      = 38400384;            // 38,400,384 region
constexpr size_t SLOT_REL    = 0;                   // 6,400,000
constexpr size_t INDEG8_REL  = 6400000;             // 3,211,264 (8*NN8*4) -> ends 9,611,264
constexpr size_t PXCD_REL    = 9611264;             // 1,605,632 (8*NN8*2) -> ends 11,216,896
constexpr size_t HIST_REL    = 0;                   // 12,812,288 (layer-3 phase)
constexpr size_t PARTS_REL   = 12812288;            // 19,218,432 -> ends 32,030,720
constexpr size_t CSR_OFF     = 76800768;            // 6,400,000
constexpr size_t OFFS_OFF    = 83200768;            // 400,128
constexpr size_t INDEG_OFF   = 83600896;            // 400,000 (totals, written by scan1)
constexpr size_t SUMS_OFF    = 84000896;            // 49,152
constexpr size_t CNT_OFF     = 84050048;            // 256
constexpr size_t DEGS_OFF    = 84050304;            // 256 (sums..degs zeroed by scan1 blk 0)
constexpr size_t PART_OFF    = 84050560;            // 512  (raw block partials from scan1)
constexpr size_t PART2_OFF   = 84051072;            // 512  (exclusive prefix, from k_fill)
constexpr size_t NSTART_OFF  = 84051584;            // 256
constexpr size_t WT0_OFF     = 84051840;            // 49,152
constexpr size_t WT1_OFF     = 84100992;            // 73,728
constexpr size_t WT2_OFF     = 84174720;            // 73,728 -> ends 84,248,448

extern "C" void kernel_launch(void* const* d_in, const int* in_sizes, int n_in,
                              void* d_out, int out_size, void* d_ws, size_t ws_size,
                              hipStream_t stream) {
    const float* x   = (const float*)d_in[0];
    const float* W0  = (const float*)d_in[1];
    const float* b0  = (const float*)d_in[2];
    const float* W1  = (const float*)d_in[3];
    const float* b1  = (const float*)d_in[4];
    const float* W2  = (const float*)d_in[5];
    const float* b2  = (const float*)d_in[6];
    const float* W3  = (const float*)d_in[7];
    const float* b3  = (const float*)d_in[8];
    const float* Wfc = (const float*)d_in[9];
    const float* bfc = (const float*)d_in[10];
    const int*   ei  = (const int*)d_in[11];
    const int*   bat = (const int*)d_in[12];
    float* out = (float*)d_out;

    char* ws = (char*)d_ws;
    unsigned short* A0  = (unsigned short*)(ws + A0_OFF);
    unsigned short* A1  = (unsigned short*)(ws + A1_OFF);
    int* slot            = (int*)(ws + A1_OFF + SLOT_REL);
    int* indeg8          = (int*)(ws + A1_OFF + INDEG8_REL);
    unsigned short* pxcd = (unsigned short*)(ws + A1_OFF + PXCD_REL);
    unsigned int* hist   = (unsigned int*)(ws + A1_OFF + HIST_REL);
    float* parts         = (float*)(ws + A1_OFF + PARTS_REL);
    int* csr    = (int*)(ws + CSR_OFF);
    int* offs   = (int*)(ws + OFFS_OFF);
    int* indeg  = (int*)(ws + INDEG_OFF);
    int* part   = (int*)(ws + PART_OFF);
    int* part2  = (int*)(ws + PART2_OFF);
    int* nstart = (int*)(ws + NSTART_OFF);
    unsigned short* Wt0 = (unsigned short*)(ws + WT0_OFF);
    unsigned short* Wt1 = (unsigned short*)(ws + WT1_OFF);
    unsigned short* Wt2 = (unsigned short*)(ws + WT2_OFF);
    float* sums   = (float*)(ws + SUMS_OFF);
    float* cnt    = (float*)(ws + CNT_OFF);
    float* degsum = (float*)(ws + DEGS_OFF);

    // one memset: the 8 replicated counter arrays (sums/cnt/degsum zeroed by scan1 blk 0)
    hipMemsetAsync(ws + A1_OFF + INDEG8_REL, 0, 3211264, stream);

    // fused preprocessing (indeg section first: atomics hide under convx streaming)
    k_prep<<<PREP_GRID, 256, 0, stream>>>(x, ei, bat, W0, W1, W2, A0, indeg8, slot,
                                          Wt0, Wt1, Wt2, nstart);

    // merge copies + block-local scan; fill recomputes 98-partial prefix, publishes part2
    k_scan1<<<NB_SCAN, 1024, 0, stream>>>(indeg8, indeg, pxcd, offs, part, sums);
    k_fill<<<(NE / 4 + 255) / 256, 256, 0, stream>>>(ei, offs, part, slot, pxcd, csr, part2);

    const int AGG_GRID  = NN / 4;                   // 25000 blocks
    const int GEMM_GRID = (NN / 32 + 3) / 4;        // 782 blocks

    // layers 0..2 (agg A0 -> A1, gemm A1 -> A0)
    k_agg128<<<AGG_GRID, 256, 0, stream>>>(A0, A1, offs, part2, indeg, csr);
    k_gemm<128, 192><<<GEMM_GRID, 256, 0, stream>>>(A1, Wt0, b0, A0);
    k_agg192<<<AGG_GRID, 256, 0, stream>>>(A0, A1, offs, part2, indeg, csr);
    k_gemm<192, 192><<<GEMM_GRID, 256, 0, stream>>>(A1, Wt1, b1, A0);
    k_agg192<<<AGG_GRID, 256, 0, stream>>>(A0, A1, offs, part2, indeg, csr);
    k_gemm<192, 192><<<GEMM_GRID, 256, 0, stream>>>(A1, Wt2, b2, A0);   // x3 -> A0

    // layer 3 via linearity: pooled(y3) = pooled(x3) + eps*degsum + E @ relu(x3)
    k_histpool<<<2256, 256, 0, stream>>>(csr, offs, part2, nstart, hist, A0, bat, indeg,
                                         sums, cnt, degsum);
    k_egemm<<<EG_BLOCKS, 384, 0, stream>>>(A0, hist, parts);
    k_head<<<NG, 192, 0, stream>>>(sums, parts, cnt, degsum, W3, b3, Wfc, bfc, out);
}

// Round 11
// 607.894 us; speedup vs baseline: 1.0677x; 1.0677x over previous
//
#include <hip/hip_runtime.h>
#include <hip/hip_bf16.h>
#include <stdint.h>

// ---------------- problem constants ----------------
constexpr int NN = 100000;     // nodes
constexpr int NE = 1600000;    // edges
constexpr int NG = 64;         // graphs
constexpr int S  = 192;        // row stride (elements) for node-feature buffers
constexpr int NB_SCAN = 98;    // ceil(100000/1024)
constexpr int NN8 = 100352;    // per-copy stride for replicated counters
constexpr unsigned int ZOFF = (unsigned int)NN * 384u;   // byte offset of the zero row

// prep kernel grid sections (indeg+slot FIRST | convx | convw(W0..W2) | nstart)
constexpr int PREP_INDEG_BLK = 1563;    // ceil(NE/4/256), 4 edges/thread
constexpr int PREP_CONVX_BLK = 12500;   // NN*32/256
constexpr int PREP_CONVW_BLK = 384;     // (24576+36864+36864)/256
constexpr int PREP_GB_BLK    = 391;     // ceil(NN/256)
constexpr int PREP_GRID = PREP_INDEG_BLK + PREP_CONVX_BLK + PREP_CONVW_BLK + PREP_GB_BLK;

// E-GEMM geometry
constexpr int EG_BLOCKS = 391;            // ceil(NN/256), 256 src rows per block
constexpr int HROW = 50048;               // hist row length in u32 (EG_BLOCKS*256/2)
constexpr int SROW = HROW / 8;            // 6256 u32 = 25KB LDS slice

typedef __bf16 bf16x8 __attribute__((ext_vector_type(8)));
typedef float  f32x16 __attribute__((ext_vector_type(16)));
typedef float  f32x2  __attribute__((ext_vector_type(2)));

union U16x4 { uint4 u; bf16x8 b; };

// bf16(packed in uint halves) <-> f32 helpers
__device__ __forceinline__ float bl(unsigned int u) { return __uint_as_float(u << 16); }
__device__ __forceinline__ float bh(unsigned int u) { return __uint_as_float(u & 0xffff0000u); }
__device__ __forceinline__ float b16f(unsigned short u) { return __uint_as_float(((unsigned int)u) << 16); }
__device__ __forceinline__ unsigned int fb(float f) {  // f32 -> bf16 bits, RTNE
    unsigned int u = __float_as_uint(f);
    return (u + 0x7fffu + ((u >> 16) & 1u)) >> 16;
}
// packed bf16 relu: v_pk_max_f16 on raw bits decides on sign/zero only — exact for bf16.
__device__ __forceinline__ unsigned int prelu(unsigned int u) {
    unsigned int r;
    asm("v_pk_max_f16 %0, %1, %2" : "=v"(r) : "v"(u), "v"(0u));
    return r;
}
// two u16 counts -> packed bf16 pair (exact for counts <= 256)
__device__ __forceinline__ unsigned int cnt2bf(unsigned int h) {
    float f0 = (float)(h & 0xffffu);
    float f1 = (float)(h >> 16);
    return (__float_as_uint(f0) >> 16) | (__float_as_uint(f1) & 0xffff0000u);
}

// ---------------- fused preprocessing: indeg8+slot | convx | convw | nstart ----------------
// indeg counters replicated 8x, copy chosen by blockIdx&7 (presumed XCD). Copy selector
// is a deterministic function of blockIdx, recomputed by k_fill, so correctness does
// NOT depend on the actual XCD mapping.
__global__ __launch_bounds__(256) void k_prep(const float* __restrict__ x,
                                              const int* __restrict__ ei,
                                              const int* __restrict__ bat,
                                              const float* __restrict__ W0, const float* __restrict__ W1,
                                              const float* __restrict__ W2,
                                              unsigned short* __restrict__ A_,
                                              int* __restrict__ indeg8, int* __restrict__ slot,
                                              unsigned short* __restrict__ T0, unsigned short* __restrict__ T1,
                                              unsigned short* __restrict__ T2,
                                              int* __restrict__ nstart) {
    const int b = blockIdx.x;
    if (b < PREP_INDEG_BLK) {
        int e4 = (b * 256 + threadIdx.x) * 4;
        if (e4 < NE) {
            int* cp = indeg8 + (b & 7) * NN8;
            int4 d = *(const int4*)(ei + NE + e4);
            int4 sl;
            sl.x = atomicAdd(&cp[d.x], 1);
            sl.y = atomicAdd(&cp[d.y], 1);
            sl.z = atomicAdd(&cp[d.z], 1);
            sl.w = atomicAdd(&cp[d.w], 1);
            *(int4*)(slot + e4) = sl;
        }
    } else if (b < PREP_INDEG_BLK + PREP_CONVX_BLK) {
        int id = (b - PREP_INDEG_BLK) * 256 + threadIdx.x;
        if (id < 96) ((unsigned int*)(A_ + (size_t)NN * S))[id] = 0u;   // zero sentinel row
        int row = id >> 5, c4 = id & 31;
        float4 v = ((const float4*)x)[id];
        uint2 a;
        a.x = fb(v.x) | (fb(v.y) << 16);
        a.y = fb(v.z) | (fb(v.w) << 16);
        *(uint2*)(A_ + row * S + c4 * 4) = a;
    } else if (b < PREP_INDEG_BLK + PREP_CONVX_BLK + PREP_CONVW_BLK) {
        int id = (b - PREP_INDEG_BLK - PREP_CONVX_BLK) * 256 + threadIdx.x;
        const float* W; unsigned short* T; int N, base;
        if      (id < 24576) { W = W0; T = T0; N = 192; base = 0;     }
        else if (id < 61440) { W = W1; T = T1; N = 192; base = 24576; }
        else                 { W = W2; T = T2; N = 192; base = 61440; }
        int lid = id - base;
        int ci = lid >> 3, j = lid & 7;
        int kc = ci / N, n = ci % N;
        T[lid] = (unsigned short)fb(W[(kc * 8 + j) * N + n]);
    } else {
        // nstart[g] = first node n with bat[n] >= g (batch sorted); empty graphs ok
        int n = (b - PREP_INDEG_BLK - PREP_CONVX_BLK - PREP_CONVW_BLK) * 256 + threadIdx.x;
        if (n < NN) {
            int b0 = bat[n];
            int bprev = (n == 0) ? -1 : bat[n - 1];
            for (int g = bprev + 1; g <= b0; g++) nstart[g] = n;
            if (n == NN - 1)
                for (int g = b0 + 1; g < NG; g++) nstart[g] = NN;
        }
    }
}

// ---------------- scan: merge 8 counter copies -> indeg, pxcd, offs; zero sums ----------------
__global__ __launch_bounds__(1024) void k_scan1(const int* __restrict__ indeg8,
                                                int* __restrict__ indeg,
                                                unsigned short* __restrict__ pxcd,
                                                int* __restrict__ offs,
                                                int* __restrict__ partials,
                                                float* __restrict__ zero_region) {
    __shared__ int s[1024];
    int t = threadIdx.x;
    int gid = blockIdx.x * 1024 + t;
    int v = 0;
    if (gid < NN) {
        int run = 0;
#pragma unroll
        for (int x = 0; x < 8; x++) {
            int c = indeg8[x * NN8 + gid];
            pxcd[x * NN8 + gid] = (unsigned short)run;   // exclusive prefix over copies
            run += c;
        }
        v = run;
        indeg[gid] = run;
    }
    if (blockIdx.x == 0) {   // fold: zero sums+cnt+degsum (12,416 floats, contiguous)
        for (int i = t; i < 12416; i += 1024) zero_region[i] = 0.f;
    }
    s[t] = v;
    __syncthreads();
    for (int d = 1; d < 1024; d <<= 1) {
        int tv = (t >= d) ? s[t - d] : 0;
        __syncthreads();
        s[t] += tv;
        __syncthreads();
    }
    if (gid < NN) offs[gid + 1] = s[t];
    if (t == 1023) partials[blockIdx.x] = s[1023];
}

// true exclusive offset of node j (offs holds block-local inclusive scans; part = exclusive
// prefix of block partials, published by k_fill block 0)
__device__ __forceinline__ int toff(const int* __restrict__ offs, const int* __restrict__ part, int j) {
    return j ? (offs[j] + part[(j - 1) >> 10]) : 0;
}

// ---------------- CSR fill (98-entry partial prefix recomputed in LDS) ----------------
__global__ __launch_bounds__(256) void k_fill(const int* __restrict__ ei, const int* __restrict__ offs,
                                              const int* __restrict__ praw,
                                              const int* __restrict__ slot,
                                              const unsigned short* __restrict__ pxcd,
                                              int* __restrict__ csr,
                                              int* __restrict__ part2) {
    __shared__ int s[128];
    __shared__ int spx[128];
    const int t = threadIdx.x;
    int v = 0;
    if (t < 128) {
        v = (t < NB_SCAN) ? praw[t] : 0;
        s[t] = v;
    }
    __syncthreads();
    for (int d = 1; d < 128; d <<= 1) {
        int tv = (t < 128 && t >= d) ? s[t - d] : 0;
        __syncthreads();
        if (t < 128) s[t] += tv;
        __syncthreads();
    }
    if (t < 128) spx[t] = s[t] - v;          // exclusive prefix of partials
    __syncthreads();
    if (blockIdx.x == 0 && t < NB_SCAN) part2[t] = spx[t];

    int e4 = (blockIdx.x * 256 + t) * 4;
    if (e4 >= NE) return;
    const unsigned short* px = pxcd + (size_t)((e4 >> 10) & 7) * NN8;   // prep copy of this edge block
    int4 sv = *(const int4*)(ei + e4);
    int4 dv = *(const int4*)(ei + NE + e4);
    int4 sl = *(const int4*)(slot + e4);
    csr[(dv.x ? offs[dv.x] + spx[(dv.x - 1) >> 10] : 0) + px[dv.x] + sl.x] = sv.x;
    csr[(dv.y ? offs[dv.y] + spx[(dv.y - 1) >> 10] : 0) + px[dv.y] + sl.y] = sv.y;
    csr[(dv.z ? offs[dv.z] + spx[(dv.z - 1) >> 10] : 0) + px[dv.z] + sl.z] = sv.z;
    csr[(dv.w ? offs[dv.w] + spx[(dv.w - 1) >> 10] : 0) + px[dv.w] + sl.w] = sv.w;
}

// ---------------- aggregation (layers 0..2) — round-7-proven structure ----------------
__global__ __launch_bounds__(256, 8) void k_agg192(const unsigned short* __restrict__ Ain,
                                                   unsigned short* __restrict__ Yout,
                                                   const int* __restrict__ offs,
                                                   const int* __restrict__ part,
                                                   const int* __restrict__ indeg,
                                                   const int* __restrict__ csr) {
    const int w = threadIdx.x >> 6, lane = threadIdx.x & 63;
    const int i = __builtin_amdgcn_readfirstlane(blockIdx.x * 4 + w);
    const bool act = lane < 48;
    const int deg   = __builtin_amdgcn_readfirstlane(indeg[i]);
    const int start = __builtin_amdgcn_readfirstlane(toff(offs, part, i));
    const int fo = (act ? lane : 47) * 8;
    const char* Ab = (const char*)Ain;

    f32x2 A01, A23;
    {
        uint2 p = *(const uint2*)(Ab + (size_t)i * 384 + fo);
        const float ed = 1e-7f * (float)deg;
        A01 = (f32x2){bl(p.x) + ed, bh(p.x) + ed};
        A23 = (f32x2){bl(p.y) + ed, bh(p.y) + ed};
    }

    const int* ecsr = csr + start;
    for (int e = 0; e < deg; e += 16) {
        unsigned int off[16];
#pragma unroll
        for (int k = 0; k < 16; k++) {
            int v = ecsr[e + k];
            off[k] = (e + k < deg) ? (unsigned int)v * 384u : ZOFF;
        }
        uint2 p[16];
#pragma unroll
        for (int k = 0; k < 16; k++)
            p[k] = *(const uint2*)(Ab + (size_t)off[k] + fo);
#pragma unroll
        for (int k = 0; k < 16; k++) {
            unsigned int rx = prelu(p[k].x), ry = prelu(p[k].y);
            A01 += (f32x2){bl(rx), bh(rx)};
            A23 += (f32x2){bl(ry), bh(ry)};
        }
    }
    if (act) {
        uint2 o;
        o.x = fb(A01.x) | (fb(A01.y) << 16);
        o.y = fb(A23.x) | (fb(A23.y) << 16);
        *(uint2*)(Yout + (size_t)i * S + lane * 4) = o;
    }
}

__global__ __launch_bounds__(256, 8) void k_agg128(const unsigned short* __restrict__ Ain,
                                                   unsigned short* __restrict__ Yout,
                                                   const int* __restrict__ offs,
                                                   const int* __restrict__ part,
                                                   const int* __restrict__ indeg,
                                                   const int* __restrict__ csr) {
    const int w = threadIdx.x >> 6, lane = threadIdx.x & 63;
    const int i = __builtin_amdgcn_readfirstlane(blockIdx.x * 4 + w);
    const int deg   = __builtin_amdgcn_readfirstlane(indeg[i]);
    const int start = __builtin_amdgcn_readfirstlane(toff(offs, part, i));
    const int fo = lane * 4;
    const char* Ab = (const char*)Ain;

    f32x2 A01;
    {
        unsigned int p = *(const unsigned int*)(Ab + (size_t)i * 384 + fo);
        const float ed = 1e-7f * (float)deg;
        A01 = (f32x2){bl(p) + ed, bh(p) + ed};
    }

    const int* ecsr = csr + start;
    for (int e = 0; e < deg; e += 16) {
        unsigned int off[16];
#pragma unroll
        for (int k = 0; k < 16; k++) {
            int v = ecsr[e + k];
            off[k] = (e + k < deg) ? (unsigned int)v * 384u : ZOFF;
        }
        unsigned int q[16];
#pragma unroll
        for (int k = 0; k < 16; k++)
            q[k] = *(const unsigned int*)(Ab + (size_t)off[k] + fo);
#pragma unroll
        for (int k = 0; k < 16; k++) {
            unsigned int r = prelu(q[k]);
            A01 += (f32x2){bl(r), bh(r)};
        }
    }
    *(unsigned int*)(Yout + (size_t)i * S + lane * 2) =
        fb(A01.x) | (fb(A01.y) << 16);
}

// ---------------- GEMM: h = y @ W + b (layers 0..2) ----------------
template <int K, int N>
__global__ __launch_bounds__(256) void k_gemm(const unsigned short* __restrict__ Yin,
                                              const unsigned short* __restrict__ WtC,
                                              const float* __restrict__ bias,
                                              unsigned short* __restrict__ Aout) {
    static_assert(K % 16 == 0 && N % 32 == 0, "");
    const int w = threadIdx.x >> 6, lane = threadIdx.x & 63;
    const int rt = blockIdx.x * 4 + w;
    if (rt >= (NN / 32)) return;
    const int hl = lane >> 5, lr = lane & 31;
    const int row0 = rt * 32;
    f32x16 acc[N / 32];
#pragma unroll
    for (int c = 0; c < N / 32; c++)
#pragma unroll
        for (int r = 0; r < 16; r++) acc[c][r] = 0.f;

    const unsigned short* ap = Yin + (row0 + lr) * S + hl * 8;
    const uint4* b4 = (const uint4*)WtC;
#pragma unroll
    for (int ks = 0; ks < K / 16; ks++) {
        U16x4 a;
        a.u = *(const uint4*)(ap + ks * 16);
#pragma unroll
        for (int c = 0; c < N / 32; c++) {
            U16x4 b;
            b.u = b4[(ks * 2 + hl) * N + c * 32 + lr];
            acc[c] = __builtin_amdgcn_mfma_f32_32x32x16_bf16(a.b, b.b, acc[c], 0, 0, 0);
        }
    }
#pragma unroll
    for (int c = 0; c < N / 32; c++) {
        const int col = c * 32 + lr;
        const float bc = bias[col];
#pragma unroll
        for (int r = 0; r < 16; r++) {
            const int row = row0 + (r & 3) + 8 * (r >> 2) + 4 * hl;
            Aout[row * S + col] = (unsigned short)fb(acc[c][r] + bc);
        }
    }
}

// ---------------- fused hist (LDS, zero global atomics) + pool ----------------
// Blocks 0..511: hist slice (g=b>>3, s=b&7). Each block zeroes a 25KB LDS slice,
// scans the graph's csr range filtering to its 6256-bin slice, accumulates with LDS
// atomics (same-address serialization confined to the CU), then streams the slice to
// global with plain stores. Replaces 1.6M global atomic RMWs with LDS ops.
// Blocks 512..2511: pooling over x3, 50 nodes/block.
__global__ __launch_bounds__(256) void k_histpool(const int* __restrict__ csr,
                                                  const int* __restrict__ offs,
                                                  const int* __restrict__ part,
                                                  const int* __restrict__ nstart,
                                                  unsigned int* __restrict__ hist,
                                                  const unsigned short* __restrict__ X3,
                                                  const int* __restrict__ bat,
                                                  const int* __restrict__ indeg,
                                                  float* __restrict__ sums, float* __restrict__ cnt,
                                                  float* __restrict__ degsum) {
    __shared__ unsigned int hlds[SROW];     // 25,024 B
    const int b = blockIdx.x;
    if (b < 512) {
        const int g = b >> 3, q = b & 7;
        const unsigned int q0 = (unsigned int)(q * SROW);
        for (int i = threadIdx.x; i < SROW; i += 256) hlds[i] = 0u;
        __syncthreads();
        const int s0 = toff(offs, part, nstart[g]);
        const int s1 = (g == NG - 1) ? NE : toff(offs, part, nstart[g + 1]);
        for (int p = s0 + threadIdx.x; p < s1; p += 256) {
            int src = csr[p];
            unsigned int h = (unsigned int)src >> 1;
            if (h - q0 < (unsigned int)SROW)
                atomicAdd(&hlds[h - q0], 1u << (16 * (src & 1)));
        }
        __syncthreads();
        unsigned int* hrow = hist + (size_t)g * HROW + q0;
        for (int i = threadIdx.x; i < SROW; i += 256) hrow[i] = hlds[i];
    } else {
        const int pb = b - 512;        // 2000 blocks x 50 nodes
        const int f = threadIdx.x;     // 192 features (64 lanes idle)
        if (f >= 192) return;
        int n0 = pb * 50;
        int n1 = min(n0 + 50, NN);
        int cur = bat[n0];
        float acc = 0.f;
        int run = 0, dacc = 0;
        for (int n = n0; n < n1; n++) {
            int g = bat[n];
            if (g != cur) {
                atomicAdd(&sums[cur * 192 + f], acc);
                if (f == 0) { atomicAdd(&cnt[cur], (float)run); atomicAdd(&degsum[cur], (float)dacc); }
                acc = 0.f; run = 0; dacc = 0; cur = g;
            }
            acc += b16f(X3[(size_t)n * S + f]);
            run++;
            if (f == 0) dacc += indeg[n];
        }
        atomicAdd(&sums[cur * 192 + f], acc);
        if (f == 0) { atomicAdd(&cnt[cur], (float)run); atomicAdd(&degsum[cur], (float)dacc); }
    }
}

// ---------------- layer-3 E-GEMM: P[g][f] += count(j->g) * relu(x3[j][f]) ----------------
__global__ __launch_bounds__(384) void k_egemm(const unsigned short* __restrict__ X3,
                                               const unsigned int* __restrict__ hist,
                                               float* __restrict__ partials) {
    const int wv = threadIdx.x >> 6, lane = threadIdx.x & 63;
    const int b = blockIdx.x;
    const int j0 = b * 256;
    const int hl = lane >> 5, lr = lane & 31;
    const int feat = wv * 32 + lr;
    f32x16 acc[2];
#pragma unroll
    for (int m = 0; m < 2; m++)
#pragma unroll
        for (int r = 0; r < 16; r++) acc[m][r] = 0.f;

    for (int kk = 0; kk < 16; kk++) {
        const int jh = (j0 >> 1) + kk * 8 + hl * 4;
        U16x4 af[2];
#pragma unroll
        for (int m = 0; m < 2; m++) {
            uint4 h = *(const uint4*)(hist + (size_t)(m * 32 + lr) * HROW + jh);
            af[m].u = (uint4){cnt2bf(h.x), cnt2bf(h.y), cnt2bf(h.z), cnt2bf(h.w)};
        }
        U16x4 bf;
#pragma unroll
        for (int tp = 0; tp < 4; tp++) {
            int je = j0 + kk * 16 + hl * 8 + tp * 2;
            int ja = min(je, NN), jb = min(je + 1, NN);   // sentinel zero row
            unsigned int u0 = X3[(size_t)ja * S + feat];
            unsigned int u1 = X3[(size_t)jb * S + feat];
            ((unsigned int*)&bf.u)[tp] = prelu(u0 | (u1 << 16));
        }
#pragma unroll
        for (int m = 0; m < 2; m++)
            acc[m] = __builtin_amdgcn_mfma_f32_32x32x16_bf16(af[m].b, bf.b, acc[m], 0, 0, 0);
    }
    float* pb = partials + (size_t)b * 12288;
#pragma unroll
    for (int m = 0; m < 2; m++)
#pragma unroll
        for (int r = 0; r < 16; r++) {
            const int g = m * 32 + (r & 3) + 8 * (r >> 2) + 4 * hl;
            pb[g * 192 + feat] = acc[m][r];
        }
}

// ---------------- head (fused partial-reduce + 2-layer MLP + log_softmax) ----------------
__global__ __launch_bounds__(192) void k_head(const float* __restrict__ sums,
                                              const float* __restrict__ partials,
                                              const float* __restrict__ cnt, const float* __restrict__ degsum,
                                              const float* __restrict__ W3, const float* __restrict__ b3,
                                              const float* __restrict__ Wfc, const float* __restrict__ bfc,
                                              float* __restrict__ out) {
    __shared__ float py[192];
    __shared__ float tl[128];
    __shared__ float lg[10];
    const int g = blockIdx.x, t = threadIdx.x;   // 192 threads = 192 feats
    const float inv = 1.f / fmaxf(cnt[g], 1.f);
    const float ed = 1e-7f * degsum[g];
    const float* pp = partials + g * 192 + t;
    float s0 = 0.f, s1 = 0.f, s2 = 0.f, s3 = 0.f;
    int p = 0;
    for (; p + 4 <= 391; p += 4) {
        s0 += pp[(size_t)(p + 0) * 12288];
        s1 += pp[(size_t)(p + 1) * 12288];
        s2 += pp[(size_t)(p + 2) * 12288];
        s3 += pp[(size_t)(p + 3) * 12288];
    }
    for (; p < 391; p++) s0 += pp[(size_t)p * 12288];
    py[t] = (sums[g * 192 + t] + ((s0 + s1) + (s2 + s3)) + ed) * inv;
    __syncthreads();
    if (t < 128) {
        float tf = b3[t];
        for (int k = 0; k < 192; k++) tf += py[k] * W3[k * 128 + t];
        tl[t] = tf;
    }
    __syncthreads();
    if (t < 10) {
        float sf = bfc[t];
        for (int f = 0; f < 128; f++) sf += tl[f] * Wfc[f * 10 + t];
        lg[t] = sf;
    }
    __syncthreads();
    if (t < 10) {
        float m = lg[0];
        for (int k = 1; k < 10; k++) m = fmaxf(m, lg[k]);
        float se = 0.f;
        for (int k = 0; k < 10; k++) se += expf(lg[k] - m);
        out[g * 10 + t] = lg[t] - m - logf(se);
    }
}

// ---------------- workspace layout (bytes) ----------------
// A1 region phases: [slot 6.4MB | indeg8 3.21MB | pxcd 1.6MB] (pre-CSR, all dead after
// k_fill) -> y buffer (agg/gemm) -> hist/partials (layer 3). A0 carries the zero row.
constexpr size_t A0_OFF      = 0;                   // 38,400,384 (incl zero row NN)
constexpr size_t A1_OFF      = 38400384;            // 38,400,384 region
constexpr size_t SLOT_REL    = 0;                   // 6,400,000
constexpr size_t INDEG8_REL  = 6400000;             // 3,211,264 (8*NN8*4) -> ends 9,611,264
constexpr size_t PXCD_REL    = 9611264;             // 1,605,632 (8*NN8*2) -> ends 11,216,896
constexpr size_t HIST_REL    = 0;                   // 12,812,288 (layer-3 phase)
constexpr size_t PARTS_REL   = 12812288;            // 19,218,432 -> ends 32,030,720
constexpr size_t CSR_OFF     = 76800768;            // 6,400,000
constexpr size_t OFFS_OFF    = 83200768;            // 400,128
constexpr size_t INDEG_OFF   = 83600896;            // 400,000 (totals, written by scan1)
constexpr size_t SUMS_OFF    = 84000896;            // 49,152
constexpr size_t CNT_OFF     = 84050048;            // 256
constexpr size_t DEGS_OFF    = 84050304;            // 256 (sums..degs zeroed by scan1 blk 0)
constexpr size_t PART_OFF    = 84050560;            // 512  (raw block partials from scan1)
constexpr size_t PART2_OFF   = 84051072;            // 512  (exclusive prefix, from k_fill)
constexpr size_t NSTART_OFF  = 84051584;            // 256
constexpr size_t WT0_OFF     = 84051840;            // 49,152
constexpr size_t WT1_OFF     = 84100992;            // 73,728
constexpr size_t WT2_OFF     = 84174720;            // 73,728 -> ends 84,248,448

extern "C" void kernel_launch(void* const* d_in, const int* in_sizes, int n_in,
                              void* d_out, int out_size, void* d_ws, size_t ws_size,
                              hipStream_t stream) {
    const float* x   = (const float*)d_in[0];
    const float* W0  = (const float*)d_in[1];
    const float* b0  = (const float*)d_in[2];
    const float* W1  = (const float*)d_in[3];
    const float* b1  = (const float*)d_in[4];
    const float* W2  = (const float*)d_in[5];
    const float* b2  = (const float*)d_in[6];
    const float* W3  = (const float*)d_in[7];
    const float* b3  = (const float*)d_in[8];
    const float* Wfc = (const float*)d_in[9];
    const float* bfc = (const float*)d_in[10];
    const int*   ei  = (const int*)d_in[11];
    const int*   bat = (const int*)d_in[12];
    float* out = (float*)d_out;

    char* ws = (char*)d_ws;
    unsigned short* A0  = (unsigned short*)(ws + A0_OFF);
    unsigned short* A1  = (unsigned short*)(ws + A1_OFF);
    int* slot            = (int*)(ws + A1_OFF + SLOT_REL);
    int* indeg8          = (int*)(ws + A1_OFF + INDEG8_REL);
    unsigned short* pxcd = (unsigned short*)(ws + A1_OFF + PXCD_REL);
    unsigned int* hist   = (unsigned int*)(ws + A1_OFF + HIST_REL);
    float* parts         = (float*)(ws + A1_OFF + PARTS_REL);
    int* csr    = (int*)(ws + CSR_OFF);
    int* offs   = (int*)(ws + OFFS_OFF);
    int* indeg  = (int*)(ws + INDEG_OFF);
    int* part   = (int*)(ws + PART_OFF);
    int* part2  = (int*)(ws + PART2_OFF);
    int* nstart = (int*)(ws + NSTART_OFF);
    unsigned short* Wt0 = (unsigned short*)(ws + WT0_OFF);
    unsigned short* Wt1 = (unsigned short*)(ws + WT1_OFF);
    unsigned short* Wt2 = (unsigned short*)(ws + WT2_OFF);
    float* sums   = (float*)(ws + SUMS_OFF);
    float* cnt    = (float*)(ws + CNT_OFF);
    float* degsum = (float*)(ws + DEGS_OFF);

    // one memset: the 8 replicated counter arrays (sums/cnt/degsum zeroed by scan1 blk 0)
    hipMemsetAsync(ws + A1_OFF + INDEG8_REL, 0, 3211264, stream);

    // fused preprocessing (indeg section first: atomics hide under convx streaming)
    k_prep<<<PREP_GRID, 256, 0, stream>>>(x, ei, bat, W0, W1, W2, A0, indeg8, slot,
                                          Wt0, Wt1, Wt2, nstart);

    // merge copies + block-local scan; fill recomputes 98-partial prefix, publishes part2
    k_scan1<<<NB_SCAN, 1024, 0, stream>>>(indeg8, indeg, pxcd, offs, part, sums);
    k_fill<<<(NE / 4 + 255) / 256, 256, 0, stream>>>(ei, offs, part, slot, pxcd, csr, part2);

    const int AGG_GRID  = NN / 4;                   // 25000 blocks
    const int GEMM_GRID = (NN / 32 + 3) / 4;        // 782 blocks

    // layers 0..2 (agg A0 -> A1, gemm A1 -> A0)
    k_agg128<<<AGG_GRID, 256, 0, stream>>>(A0, A1, offs, part2, indeg, csr);
    k_gemm<128, 192><<<GEMM_GRID, 256, 0, stream>>>(A1, Wt0, b0, A0);
    k_agg192<<<AGG_GRID, 256, 0, stream>>>(A0, A1, offs, part2, indeg, csr);
    k_gemm<192, 192><<<GEMM_GRID, 256, 0, stream>>>(A1, Wt1, b1, A0);
    k_agg192<<<AGG_GRID, 256, 0, stream>>>(A0, A1, offs, part2, indeg, csr);
    k_gemm<192, 192><<<GEMM_GRID, 256, 0, stream>>>(A1, Wt2, b2, A0);   // x3 -> A0

    // layer 3 via linearity: pooled(y3) = pooled(x3) + eps*degsum + E @ relu(x3)
    // (hist rows fully overwritten by the LDS slices — no pre-zero needed)
    k_histpool<<<2512, 256, 0, stream>>>(csr, offs, part2, nstart, hist, A0, bat, indeg,
                                         sums, cnt, degsum);
    k_egemm<<<EG_BLOCKS, 384, 0, stream>>>(A0, hist, parts);
    k_head<<<NG, 192, 0, stream>>>(sums, parts, cnt, degsum, W3, b3, Wfc, bfc, out);
}